// Round 11
// baseline (298.551 us; speedup 1.0000x reference)
//
#include <hip/hip_runtime.h>
#include <math.h>

#define DIN 256
#define HDIM 128
#define NCRIT 10
#define CAP 96

typedef __bf16 bf16;
typedef bf16 bf16x8 __attribute__((ext_vector_type(8)));
typedef float f32x4 __attribute__((ext_vector_type(4)));
typedef float f32x2 __attribute__((ext_vector_type(2)));

static inline size_t alignup(size_t x, size_t a) { return (x + a - 1) & ~(a - 1); }

__device__ inline float bflo(unsigned v) { return __uint_as_float(v << 16); }
__device__ inline float bfhi(unsigned v) { return __uint_as_float(v & 0xffff0000u); }

__device__ inline bf16x8 cvt8(float4 v0, float4 v1) {
    bf16x8 w;
    w[0] = (bf16)v0.x; w[1] = (bf16)v0.y; w[2] = (bf16)v0.z; w[3] = (bf16)v0.w;
    w[4] = (bf16)v1.x; w[5] = (bf16)v1.y; w[6] = (bf16)v1.z; w[7] = (bf16)v1.w;
    return w;
}

__device__ inline unsigned char f32_fp8(float f) {
    return (unsigned char)(__builtin_amdgcn_cvt_pk_fp8_f32(f, f, 0, false) & 0xFF);
}

__device__ inline void gl_lds16(const void* g, void* l) {
    __builtin_amdgcn_global_load_lds(
        (const __attribute__((address_space(1))) unsigned*)g,
        (__attribute__((address_space(3))) unsigned*)l, 16, 0, 0);
}

// ---------- fused bucket-CSR build + weight convert ----------
// blocks [0, nW): Wcat[384][256] = bf16([Wl;Wr;Wres])
// blocks [nW, ...): p = atomicAdd(cnt[dst]); sidx[dst*CAP + p] = src
__global__ void k_build(const int* __restrict__ src, const int* __restrict__ dst, int E,
                        int* __restrict__ cnt, int* __restrict__ sidx, int nW,
                        const float* __restrict__ Wl, const float* __restrict__ Wr,
                        const float* __restrict__ Wres, bf16* __restrict__ Wcat) {
    int t = threadIdx.x;
    if ((int)blockIdx.x < nW) {
        int base = (blockIdx.x * 256 + t) * 4;
        if (base >= 384 * 256) return;
        int r = base >> 8;
        int c = base & 255;
        const float* W = (r < 128) ? Wl : ((r < 256) ? Wr : Wres);
        float4 v = *(const float4*)&W[(size_t)(r & 127) * 256 + c];
        bf16* o = &Wcat[base];
        o[0] = (bf16)v.x; o[1] = (bf16)v.y; o[2] = (bf16)v.z; o[3] = (bf16)v.w;
    } else {
        int i = (blockIdx.x - nW) * 256 + t;
        if (i < E) {
            int d = dst[i];
            int p = atomicAdd(&cnt[d], 1);
            if (p < CAP) sidx[(size_t)d * CAP + p] = src[i];
        }
    }
}

// ---------- MFMA GEMM: [y|z] = x @ Wcat^T, BM=64 BN=384 BK=32, dbuf + global_load_lds ----------
// y stored fp8 e4m3 [node][128]; z bf16 [node][256]
__global__ __launch_bounds__(256) void k_gemm(const float* __restrict__ x,
                                              const bf16* __restrict__ Wcat, int n,
                                              unsigned char* __restrict__ yq,
                                              bf16* __restrict__ z) {
    __shared__ __align__(16) char smem[57344];
    int t = threadIdx.x;
    int wv = t >> 6, lane = t & 63;
    int node0 = blockIdx.x * 64;

    f32x4 acc[4][6] = {};

    int a_r = t >> 2, a_kq = t & 3;
    int a_gr = node0 + a_r;
    const float* a_src = &x[(size_t)a_gr * DIN + a_kq * 8];
    int a_woff = a_kq * 1024 + ((a_r ^ (a_kq << 1)) << 4);

    int gOff[6];
    const char* wcb = (const char*)Wcat;
    #pragma unroll
    for (int i = 0; i < 6; i++) {
        int LL = i * 256 + t;
        int kg = LL / 384;
        int c = LL - kg * 384;
        gOff[i] = c * 512 + kg * 16;
    }

    int f_kg = lane >> 4, f_l15 = lane & 15;
    int aRd[4];
    #pragma unroll
    for (int m = 0; m < 4; m++) {
        int r = m * 16 + f_l15;
        aRd[m] = f_kg * 1024 + ((r ^ (f_kg << 1)) << 4);
    }
    int bRd[6];
    #pragma unroll
    for (int nn = 0; nn < 6; nn++) {
        int c = wv * 96 + nn * 16 + f_l15;
        bRd[nn] = f_kg * 6144 + c * 16;
    }

    {
        float4 v0, v1;
        if (a_gr < n) { v0 = *(const float4*)a_src; v1 = *(const float4*)(a_src + 4); }
        else { v0 = make_float4(0, 0, 0, 0); v1 = v0; }
        *(bf16x8*)(smem + 49152 + a_woff) = cvt8(v0, v1);
        #pragma unroll
        for (int i = 0; i < 6; i++)
            gl_lds16(wcb + gOff[i], smem + i * 4096 + wv * 1024);
    }
    __syncthreads();

    #pragma unroll 2
    for (int s = 0; s < 8; ++s) {
        int cur = s & 1;
        float4 v0, v1;
        if (s < 7) {
            if (a_gr < n) {
                v0 = *(const float4*)(a_src + (s + 1) * 32);
                v1 = *(const float4*)(a_src + (s + 1) * 32 + 4);
            } else { v0 = make_float4(0, 0, 0, 0); v1 = v0; }
            #pragma unroll
            for (int i = 0; i < 6; i++)
                gl_lds16(wcb + gOff[i] + (s + 1) * 64,
                         smem + (cur ^ 1) * 24576 + i * 4096 + wv * 1024);
        }
        bf16x8 afr[4], bfr[6];
        #pragma unroll
        for (int m = 0; m < 4; m++)
            afr[m] = *(const bf16x8*)(smem + 49152 + cur * 4096 + aRd[m]);
        #pragma unroll
        for (int nn = 0; nn < 6; nn++)
            bfr[nn] = *(const bf16x8*)(smem + cur * 24576 + bRd[nn]);
        __builtin_amdgcn_s_setprio(1);
        #pragma unroll
        for (int m = 0; m < 4; m++)
            #pragma unroll
            for (int nn = 0; nn < 6; nn++)
                acc[m][nn] = __builtin_amdgcn_mfma_f32_16x16x32_bf16(
                    afr[m], bfr[nn], acc[m][nn], 0, 0, 0);
        __builtin_amdgcn_s_setprio(0);
        if (s < 7)
            *(bf16x8*)(smem + 49152 + (cur ^ 1) * 4096 + a_woff) = cvt8(v0, v1);
        __syncthreads();
    }

    // epilogue: y cols (0..127) -> fp8 region; z cols (128..383) -> bf16 region
    unsigned char* Cs8 = (unsigned char*)smem;     // [64][144] fp8
    bf16* Csz = (bf16*)(smem + 9216);              // [64][264] bf16
    #pragma unroll
    for (int m = 0; m < 4; m++) {
        #pragma unroll
        for (int nn = 0; nn < 6; nn++) {
            int col = wv * 96 + nn * 16 + f_l15;
            int r0 = m * 16 + (f_kg << 2);
            if (col < 128) {
                #pragma unroll
                for (int j = 0; j < 4; j++)
                    Cs8[(r0 + j) * 144 + col] = f32_fp8(acc[m][nn][j]);
            } else {
                #pragma unroll
                for (int j = 0; j < 4; j++)
                    Csz[(r0 + j) * 264 + (col - 128)] = (bf16)acc[m][nn][j];
            }
        }
    }
    __syncthreads();

    // y store: 64 rows x 128B fp8
    {
        #pragma unroll
        for (int h = 0; h < 2; h++) {
            int idx = h * 256 + t;
            int r = idx >> 3, ch = idx & 7;
            int gr = node0 + r;
            if (gr < n) {
                uint4 v = *(const uint4*)&Cs8[r * 144 + ch * 16];
                *(uint4*)&yq[(size_t)gr * 128 + ch * 16] = v;
            }
        }
    }
    // z store: 64 rows x 512B bf16
    {
        int r = t >> 2;
        int gr = node0 + r;
        if (gr < n) {
            #pragma unroll
            for (int u = 0; u < 8; u++) {
                int c = (t & 3) * 8 + u * 32;
                uint4 v = *(const uint4*)&Csz[r * 264 + c];
                *(uint4*)&z[(size_t)gr * 2 * HDIM + c] = v;
            }
        }
    }
}

// ---------- fused gather + epilogue: one wave per node, fp8 rows, pk-cvt ----------
__global__ __launch_bounds__(256) void k_gather(
    const unsigned char* __restrict__ yq, const bf16* __restrict__ z,
    const int* __restrict__ cnt, const int* __restrict__ sidx,
    const float* __restrict__ bl, const float* __restrict__ bres,
    const float* __restrict__ wscore, const float* __restrict__ bscore,
    const float* __restrict__ wcrit, const float* __restrict__ bcrit,
    const float* __restrict__ rrs, const float* __restrict__ palpha,
    int n, float* __restrict__ outF, float* __restrict__ outL)
{
    __shared__ bf16 wsb[11 * 128];
    int t = threadIdx.x;
    for (int i = t; i < 11 * 128; i += 256) {
        int q = i >> 7, c = i & 127;
        wsb[i] = (bf16)((q == 0) ? wscore[c] : wcrit[(size_t)(q - 1) * HDIM + c]);
    }
    __syncthreads();

    int node = blockIdx.x * 4 + (t >> 6);
    if (node >= n) return;
    int lane = t & 63, r2 = lane >> 5, c32 = lane & 31;

    // node-local loads issued early (hide under gather loop)
    uint2 zr = *(const uint2*)&z[(size_t)node * 2 * HDIM + c32 * 4];
    uint2 zs = *(const uint2*)&z[(size_t)node * 2 * HDIM + HDIM + c32 * 4];
    float4 blv = *(const float4*)&bl[c32 * 4];
    float4 brv = *(const float4*)&bres[c32 * 4];

    const unsigned char* ybase = yq + c32 * 4;
    int len = min(cnt[node], CAP);
    const int* sp = sidx + (size_t)node * CAP;

    f32x2 a01 = {0.f, 0.f}, a23 = {0.f, 0.f};
    int e = 0;
    for (; e + 8 <= len; e += 8) {
        int i0 = sp[e + r2];
        int i1 = sp[e + 2 + r2];
        int i2 = sp[e + 4 + r2];
        int i3 = sp[e + 6 + r2];
        int v0 = *(const int*)(ybase + ((size_t)(unsigned)i0 << 7));
        int v1 = *(const int*)(ybase + ((size_t)(unsigned)i1 << 7));
        int v2 = *(const int*)(ybase + ((size_t)(unsigned)i2 << 7));
        int v3 = *(const int*)(ybase + ((size_t)(unsigned)i3 << 7));
        a01 += __builtin_amdgcn_cvt_pk_f32_fp8(v0, false)
             + __builtin_amdgcn_cvt_pk_f32_fp8(v1, false)
             + __builtin_amdgcn_cvt_pk_f32_fp8(v2, false)
             + __builtin_amdgcn_cvt_pk_f32_fp8(v3, false);
        a23 += __builtin_amdgcn_cvt_pk_f32_fp8(v0, true)
             + __builtin_amdgcn_cvt_pk_f32_fp8(v1, true)
             + __builtin_amdgcn_cvt_pk_f32_fp8(v2, true)
             + __builtin_amdgcn_cvt_pk_f32_fp8(v3, true);
    }
    for (; e < len; e += 2) {
        int slot = e + r2;
        int ii = sp[slot < len ? slot : len - 1];
        int v = *(const int*)(ybase + ((size_t)(unsigned)ii << 7));
        if (slot < len) {
            a01 += __builtin_amdgcn_cvt_pk_f32_fp8(v, false);
            a23 += __builtin_amdgcn_cvt_pk_f32_fp8(v, true);
        }
    }
    float a0 = a01[0], a1 = a01[1], a2 = a23[0], a3 = a23[1];
    a0 += __shfl_xor(a0, 32, 64);
    a1 += __shfl_xor(a1, 32, 64);
    a2 += __shfl_xor(a2, 32, 64);
    a3 += __shfl_xor(a3, 32, 64);
    float inv = 1.f / fmaxf((float)len, 1.f);

    float h0 = fmaxf(a0 * inv + blv.x + bflo(zr.x), 0.f) + bflo(zs.x) + brv.x;
    float h1 = fmaxf(a1 * inv + blv.y + bfhi(zr.x), 0.f) + bfhi(zs.x) + brv.y;
    float h2 = fmaxf(a2 * inv + blv.z + bflo(zr.y), 0.f) + bflo(zs.y) + brv.z;
    float h3 = fmaxf(a3 * inv + blv.w + bfhi(zr.y), 0.f) + bfhi(zs.y) + brv.w;

    // split epilogue: half r2=0 handles q=0..5, half r2=1 handles q=6..10
    float p[6];
    #pragma unroll
    for (int qq = 0; qq < 6; qq++) {
        int q = r2 * 6 + qq;
        float s = 0.f;
        if (q < 11) {
            uint2 w = *(const uint2*)&wsb[q * 128 + c32 * 4];
            s = h0 * bflo(w.x) + h1 * bfhi(w.x) + h2 * bflo(w.y) + h3 * bfhi(w.y);
        }
        #pragma unroll
        for (int d = 1; d < 32; d <<= 1)
            s += __shfl_xor(s, d, 64);
        p[qq] = s;
    }
    if ((lane & 31) == 0) {
        if (r2 == 0) {
            float al = palpha[0];
            float aa = 1.f / (1.f + expf(-al));
            outF[node] = aa * rrs[node] + (1.f - aa) * (p[0] + bscore[0]);
            #pragma unroll
            for (int qq = 1; qq < 6; qq++)
                outL[(size_t)node * NCRIT + qq - 1] = p[qq] + bcrit[qq - 1];
        } else {
            #pragma unroll
            for (int qq = 0; qq < 5; qq++)
                outL[(size_t)node * NCRIT + 5 + qq] = p[qq] + bcrit[5 + qq];
        }
    }
}

extern "C" void kernel_launch(void* const* d_in, const int* in_sizes, int n_in,
                              void* d_out, int out_size, void* d_ws, size_t ws_size,
                              hipStream_t stream) {
    const float* x      = (const float*)d_in[0];
    const int*   ei     = (const int*)d_in[1];
    const float* rrs    = (const float*)d_in[2];
    const float* Wl     = (const float*)d_in[3];
    const float* bl     = (const float*)d_in[4];
    const float* Wr     = (const float*)d_in[5];
    const float* Wres   = (const float*)d_in[6];
    const float* bres   = (const float*)d_in[7];
    const float* wscore = (const float*)d_in[8];
    const float* bscore = (const float*)d_in[9];
    const float* wcrit  = (const float*)d_in[10];
    const float* bcrit  = (const float*)d_in[11];
    const float* alpha  = (const float*)d_in[12];

    int N = in_sizes[0] / DIN;
    int E = in_sizes[1] / 2;
    const int* srcv = ei;
    const int* dstv = ei + E;

    char* p = (char*)d_ws;
    size_t cntPad = alignup((size_t)N * 4, 256);
    int* cnt   = (int*)p; p += cntPad;
    int* sidx  = (int*)p; p += alignup((size_t)N * CAP * 4, 256);
    bf16* Wcat = (bf16*)p; p += alignup((size_t)384 * DIN * 2, 256);
    unsigned char* yq = (unsigned char*)p; p += alignup((size_t)N * HDIM, 256);
    bf16* z    = (bf16*)p; p += alignup((size_t)N * 2 * HDIM * 2, 256);

    hipMemsetAsync(cnt, 0, (size_t)N * 4, stream);

    int nW = 96;   // wconv blocks: 384*256/4/256
    k_build<<<nW + (E + 255) / 256, 256, 0, stream>>>(srcv, dstv, E, cnt, sidx, nW,
                                                      Wl, Wr, Wres, Wcat);

    k_gemm<<<(N + 63) / 64, 256, 0, stream>>>(x, Wcat, N, yq, z);

    float* outF = (float*)d_out;
    float* outL = outF + N;
    k_gather<<<(N + 3) / 4, 256, 0, stream>>>(yq, z, cnt, sidx, bl, bres,
                                              wscore, bscore, wcrit, bcrit,
                                              rrs, alpha, N, outF, outL);
}

// Round 12
// 270.746 us; speedup vs baseline: 1.1027x; 1.1027x over previous
//
#include <hip/hip_runtime.h>
#include <math.h>

#define DIN 256
#define HDIM 128
#define NCRIT 10

typedef __bf16 bf16;
typedef bf16 bf16x8 __attribute__((ext_vector_type(8)));
typedef float f32x4 __attribute__((ext_vector_type(4)));
typedef float f32x2 __attribute__((ext_vector_type(2)));

static inline size_t alignup(size_t x, size_t a) { return (x + a - 1) & ~(a - 1); }

__device__ inline float bflo(unsigned v) { return __uint_as_float(v << 16); }
__device__ inline float bfhi(unsigned v) { return __uint_as_float(v & 0xffff0000u); }

__device__ inline bf16x8 cvt8(float4 v0, float4 v1) {
    bf16x8 w;
    w[0] = (bf16)v0.x; w[1] = (bf16)v0.y; w[2] = (bf16)v0.z; w[3] = (bf16)v0.w;
    w[4] = (bf16)v1.x; w[5] = (bf16)v1.y; w[6] = (bf16)v1.z; w[7] = (bf16)v1.w;
    return w;
}

__device__ inline unsigned char f32_fp8(float f) {
    return (unsigned char)(__builtin_amdgcn_cvt_pk_fp8_f32(f, f, 0, false) & 0xFF);
}

__device__ inline void gl_lds16(const void* g, void* l) {
    __builtin_amdgcn_global_load_lds(
        (const __attribute__((address_space(1))) unsigned*)g,
        (__attribute__((address_space(3))) unsigned*)l, 16, 0, 0);
}

// ---------- k1: wconv (blocks [0,nW)) || hist (blocks [nW,...)) ----------
__global__ void k_histw(const int* __restrict__ dst, int E, int* __restrict__ cnt,
                        int* __restrict__ epos, int nW,
                        const float* __restrict__ Wl, const float* __restrict__ Wr,
                        const float* __restrict__ Wres, bf16* __restrict__ Wcat) {
    int t = threadIdx.x;
    if ((int)blockIdx.x < nW) {
        int base = (blockIdx.x * 256 + t) * 4;
        if (base >= 384 * 256) return;
        int r = base >> 8;
        int c = base & 255;
        const float* W = (r < 128) ? Wl : ((r < 256) ? Wr : Wres);
        float4 v = *(const float4*)&W[(size_t)(r & 127) * 256 + c];
        bf16* o = &Wcat[base];
        o[0] = (bf16)v.x; o[1] = (bf16)v.y; o[2] = (bf16)v.z; o[3] = (bf16)v.w;
    } else {
        int i = (blockIdx.x - nW) * 256 + t;
        if (i < E) epos[i] = atomicAdd(&cnt[dst[i]], 1);
    }
}

// ---------- k2: alloc (wave scan + atomic base) ----------
__global__ void k_alloc(const int* __restrict__ cnt, int n, int* __restrict__ off,
                        int* __restrict__ total) {
    int i = blockIdx.x * 256 + threadIdx.x;
    int lane = threadIdx.x & 63;
    int v = (i < n) ? cnt[i] : 0;
    int s = v;
    #pragma unroll
    for (int d = 1; d < 64; d <<= 1) {
        int t = __shfl_up(s, d, 64);
        if (lane >= d) s += t;
    }
    int excl = s - v;
    int wtot = __shfl(s, 63, 64);
    int base = 0;
    if (lane == 63) base = atomicAdd(total, wtot);
    base = __shfl(base, 63, 64);
    if (i < n) off[i] = base + excl;
}

// ---------- k3: gemm (blocks [0,nGemm)) || scatter (blocks [nGemm,...)) ----------
// gemm: [y|z] = x @ Wcat^T, BM=64 BN=384 BK=32, dbuf + global_load_lds
// y stored fp8 e4m3 [node][128]; z bf16 [node][256]
__global__ __launch_bounds__(256) void k_gemsc(
    const float* __restrict__ x, const bf16* __restrict__ Wcat, int n,
    unsigned char* __restrict__ yq, bf16* __restrict__ z, int nGemm,
    const int* __restrict__ src, const int* __restrict__ dstv,
    const int* __restrict__ epos, int E,
    const int* __restrict__ off, int* __restrict__ sidx) {
    __shared__ __align__(16) char smem[57344];
    int t = threadIdx.x;

    if ((int)blockIdx.x >= nGemm) {
        int i = ((int)blockIdx.x - nGemm) * 256 + t;
        if (i < E) sidx[off[dstv[i]] + epos[i]] = src[i];
        return;
    }

    int wv = t >> 6, lane = t & 63;
    int node0 = blockIdx.x * 64;

    f32x4 acc[4][6] = {};

    int a_r = t >> 2, a_kq = t & 3;
    int a_gr = node0 + a_r;
    const float* a_src = &x[(size_t)a_gr * DIN + a_kq * 8];
    int a_woff = a_kq * 1024 + ((a_r ^ (a_kq << 1)) << 4);

    int gOff[6];
    const char* wcb = (const char*)Wcat;
    #pragma unroll
    for (int i = 0; i < 6; i++) {
        int LL = i * 256 + t;
        int kg = LL / 384;
        int c = LL - kg * 384;
        gOff[i] = c * 512 + kg * 16;
    }

    int f_kg = lane >> 4, f_l15 = lane & 15;
    int aRd[4];
    #pragma unroll
    for (int m = 0; m < 4; m++) {
        int r = m * 16 + f_l15;
        aRd[m] = f_kg * 1024 + ((r ^ (f_kg << 1)) << 4);
    }
    int bRd[6];
    #pragma unroll
    for (int nn = 0; nn < 6; nn++) {
        int c = wv * 96 + nn * 16 + f_l15;
        bRd[nn] = f_kg * 6144 + c * 16;
    }

    {
        float4 v0, v1;
        if (a_gr < n) { v0 = *(const float4*)a_src; v1 = *(const float4*)(a_src + 4); }
        else { v0 = make_float4(0, 0, 0, 0); v1 = v0; }
        *(bf16x8*)(smem + 49152 + a_woff) = cvt8(v0, v1);
        #pragma unroll
        for (int i = 0; i < 6; i++)
            gl_lds16(wcb + gOff[i], smem + i * 4096 + wv * 1024);
    }
    __syncthreads();

    #pragma unroll 2
    for (int s = 0; s < 8; ++s) {
        int cur = s & 1;
        float4 v0, v1;
        if (s < 7) {
            if (a_gr < n) {
                v0 = *(const float4*)(a_src + (s + 1) * 32);
                v1 = *(const float4*)(a_src + (s + 1) * 32 + 4);
            } else { v0 = make_float4(0, 0, 0, 0); v1 = v0; }
            #pragma unroll
            for (int i = 0; i < 6; i++)
                gl_lds16(wcb + gOff[i] + (s + 1) * 64,
                         smem + (cur ^ 1) * 24576 + i * 4096 + wv * 1024);
        }
        bf16x8 afr[4], bfr[6];
        #pragma unroll
        for (int m = 0; m < 4; m++)
            afr[m] = *(const bf16x8*)(smem + 49152 + cur * 4096 + aRd[m]);
        #pragma unroll
        for (int nn = 0; nn < 6; nn++)
            bfr[nn] = *(const bf16x8*)(smem + cur * 24576 + bRd[nn]);
        __builtin_amdgcn_s_setprio(1);
        #pragma unroll
        for (int m = 0; m < 4; m++)
            #pragma unroll
            for (int nn = 0; nn < 6; nn++)
                acc[m][nn] = __builtin_amdgcn_mfma_f32_16x16x32_bf16(
                    afr[m], bfr[nn], acc[m][nn], 0, 0, 0);
        __builtin_amdgcn_s_setprio(0);
        if (s < 7)
            *(bf16x8*)(smem + 49152 + (cur ^ 1) * 4096 + a_woff) = cvt8(v0, v1);
        __syncthreads();
    }

    // epilogue: y cols (0..127) -> fp8 region; z cols (128..383) -> bf16 region
    unsigned char* Cs8 = (unsigned char*)smem;     // [64][144] fp8
    bf16* Csz = (bf16*)(smem + 9216);              // [64][264] bf16
    #pragma unroll
    for (int m = 0; m < 4; m++) {
        #pragma unroll
        for (int nn = 0; nn < 6; nn++) {
            int col = wv * 96 + nn * 16 + f_l15;
            int r0 = m * 16 + (f_kg << 2);
            if (col < 128) {
                #pragma unroll
                for (int j = 0; j < 4; j++)
                    Cs8[(r0 + j) * 144 + col] = f32_fp8(acc[m][nn][j]);
            } else {
                #pragma unroll
                for (int j = 0; j < 4; j++)
                    Csz[(r0 + j) * 264 + (col - 128)] = (bf16)acc[m][nn][j];
            }
        }
    }
    __syncthreads();

    // y store: 64 rows x 128B fp8
    {
        #pragma unroll
        for (int h = 0; h < 2; h++) {
            int idx = h * 256 + t;
            int r = idx >> 3, ch = idx & 7;
            int gr = node0 + r;
            if (gr < n) {
                uint4 v = *(const uint4*)&Cs8[r * 144 + ch * 16];
                *(uint4*)&yq[(size_t)gr * 128 + ch * 16] = v;
            }
        }
    }
    // z store: 64 rows x 512B bf16
    {
        int r = t >> 2;
        int gr = node0 + r;
        if (gr < n) {
            #pragma unroll
            for (int u = 0; u < 8; u++) {
                int c = (t & 3) * 8 + u * 32;
                uint4 v = *(const uint4*)&Csz[r * 264 + c];
                *(uint4*)&z[(size_t)gr * 2 * HDIM + c] = v;
            }
        }
    }
}

// ---------- k4: fused gather + epilogue: one wave per node, fp8 rows, pk-cvt ----------
__global__ __launch_bounds__(256) void k_gather(
    const unsigned char* __restrict__ yq, const bf16* __restrict__ z,
    const int* __restrict__ off, const int* __restrict__ cnt, const int* __restrict__ sidx,
    const float* __restrict__ bl, const float* __restrict__ bres,
    const float* __restrict__ wscore, const float* __restrict__ bscore,
    const float* __restrict__ wcrit, const float* __restrict__ bcrit,
    const float* __restrict__ rrs, const float* __restrict__ palpha,
    int n, float* __restrict__ outF, float* __restrict__ outL)
{
    __shared__ bf16 wsb[11 * 128];
    int t = threadIdx.x;
    for (int i = t; i < 11 * 128; i += 256) {
        int q = i >> 7, c = i & 127;
        wsb[i] = (bf16)((q == 0) ? wscore[c] : wcrit[(size_t)(q - 1) * HDIM + c]);
    }
    __syncthreads();

    int node = blockIdx.x * 4 + (t >> 6);
    if (node >= n) return;
    int lane = t & 63, r2 = lane >> 5, c32 = lane & 31;

    // node-local loads issued early (hide under gather loop)
    uint2 zr = *(const uint2*)&z[(size_t)node * 2 * HDIM + c32 * 4];
    uint2 zs = *(const uint2*)&z[(size_t)node * 2 * HDIM + HDIM + c32 * 4];
    float4 blv = *(const float4*)&bl[c32 * 4];
    float4 brv = *(const float4*)&bres[c32 * 4];

    const unsigned char* ybase = yq + c32 * 4;
    int beg = off[node], len = cnt[node];
    const int* sp = sidx + beg;

    f32x2 a01 = {0.f, 0.f}, a23 = {0.f, 0.f};
    int e = 0;
    for (; e + 8 <= len; e += 8) {
        int i0 = sp[e + r2];
        int i1 = sp[e + 2 + r2];
        int i2 = sp[e + 4 + r2];
        int i3 = sp[e + 6 + r2];
        int v0 = *(const int*)(ybase + ((size_t)(unsigned)i0 << 7));
        int v1 = *(const int*)(ybase + ((size_t)(unsigned)i1 << 7));
        int v2 = *(const int*)(ybase + ((size_t)(unsigned)i2 << 7));
        int v3 = *(const int*)(ybase + ((size_t)(unsigned)i3 << 7));
        a01 += __builtin_amdgcn_cvt_pk_f32_fp8(v0, false)
             + __builtin_amdgcn_cvt_pk_f32_fp8(v1, false)
             + __builtin_amdgcn_cvt_pk_f32_fp8(v2, false)
             + __builtin_amdgcn_cvt_pk_f32_fp8(v3, false);
        a23 += __builtin_amdgcn_cvt_pk_f32_fp8(v0, true)
             + __builtin_amdgcn_cvt_pk_f32_fp8(v1, true)
             + __builtin_amdgcn_cvt_pk_f32_fp8(v2, true)
             + __builtin_amdgcn_cvt_pk_f32_fp8(v3, true);
    }
    for (; e < len; e += 2) {
        int slot = e + r2;
        int ii = sp[slot < len ? slot : len - 1];
        int v = *(const int*)(ybase + ((size_t)(unsigned)ii << 7));
        if (slot < len) {
            a01 += __builtin_amdgcn_cvt_pk_f32_fp8(v, false);
            a23 += __builtin_amdgcn_cvt_pk_f32_fp8(v, true);
        }
    }
    float a0 = a01[0], a1 = a01[1], a2 = a23[0], a3 = a23[1];
    a0 += __shfl_xor(a0, 32, 64);
    a1 += __shfl_xor(a1, 32, 64);
    a2 += __shfl_xor(a2, 32, 64);
    a3 += __shfl_xor(a3, 32, 64);
    float inv = 1.f / fmaxf((float)len, 1.f);

    float h0 = fmaxf(a0 * inv + blv.x + bflo(zr.x), 0.f) + bflo(zs.x) + brv.x;
    float h1 = fmaxf(a1 * inv + blv.y + bfhi(zr.x), 0.f) + bfhi(zs.x) + brv.y;
    float h2 = fmaxf(a2 * inv + blv.z + bflo(zr.y), 0.f) + bflo(zs.y) + brv.z;
    float h3 = fmaxf(a3 * inv + blv.w + bfhi(zr.y), 0.f) + bfhi(zs.y) + brv.w;

    // split epilogue: half r2=0 handles q=0..5, half r2=1 handles q=6..10
    float p[6];
    #pragma unroll
    for (int qq = 0; qq < 6; qq++) {
        int q = r2 * 6 + qq;
        float s = 0.f;
        if (q < 11) {
            uint2 w = *(const uint2*)&wsb[q * 128 + c32 * 4];
            s = h0 * bflo(w.x) + h1 * bfhi(w.x) + h2 * bflo(w.y) + h3 * bfhi(w.y);
        }
        #pragma unroll
        for (int d = 1; d < 32; d <<= 1)
            s += __shfl_xor(s, d, 64);
        p[qq] = s;
    }
    if ((lane & 31) == 0) {
        if (r2 == 0) {
            float al = palpha[0];
            float aa = 1.f / (1.f + expf(-al));
            outF[node] = aa * rrs[node] + (1.f - aa) * (p[0] + bscore[0]);
            #pragma unroll
            for (int qq = 1; qq < 6; qq++)
                outL[(size_t)node * NCRIT + qq - 1] = p[qq] + bcrit[qq - 1];
        } else {
            #pragma unroll
            for (int qq = 0; qq < 5; qq++)
                outL[(size_t)node * NCRIT + 5 + qq] = p[qq] + bcrit[5 + qq];
        }
    }
}

extern "C" void kernel_launch(void* const* d_in, const int* in_sizes, int n_in,
                              void* d_out, int out_size, void* d_ws, size_t ws_size,
                              hipStream_t stream) {
    const float* x      = (const float*)d_in[0];
    const int*   ei     = (const int*)d_in[1];
    const float* rrs    = (const float*)d_in[2];
    const float* Wl     = (const float*)d_in[3];
    const float* bl     = (const float*)d_in[4];
    const float* Wr     = (const float*)d_in[5];
    const float* Wres   = (const float*)d_in[6];
    const float* bres   = (const float*)d_in[7];
    const float* wscore = (const float*)d_in[8];
    const float* bscore = (const float*)d_in[9];
    const float* wcrit  = (const float*)d_in[10];
    const float* bcrit  = (const float*)d_in[11];
    const float* alpha  = (const float*)d_in[12];

    int N = in_sizes[0] / DIN;
    int E = in_sizes[1] / 2;
    const int* srcv = ei;
    const int* dstv = ei + E;

    char* p = (char*)d_ws;
    size_t cntPad = alignup((size_t)N * 4, 256);
    int* cnt   = (int*)p; p += cntPad;
    int* total = (int*)p; p += 256;
    int* off   = (int*)p; p += alignup((size_t)N * 4, 256);
    int* epos  = (int*)p; p += alignup((size_t)E * 4, 256);
    int* sidx  = (int*)p; p += alignup((size_t)E * 4, 256);
    bf16* Wcat = (bf16*)p; p += alignup((size_t)384 * DIN * 2, 256);
    unsigned char* yq = (unsigned char*)p; p += alignup((size_t)N * HDIM, 256);
    bf16* z    = (bf16*)p; p += alignup((size_t)N * 2 * HDIM * 2, 256);

    // single memset covers cnt + total (adjacent)
    hipMemsetAsync(cnt, 0, cntPad + 256, stream);

    int nW = 96;   // wconv blocks
    k_histw<<<nW + (E + 255) / 256, 256, 0, stream>>>(dstv, E, cnt, epos, nW,
                                                      Wl, Wr, Wres, Wcat);
    k_alloc<<<(N + 255) / 256, 256, 0, stream>>>(cnt, N, off, total);

    int nGemm = (N + 63) / 64;
    k_gemsc<<<nGemm + (E + 255) / 256, 256, 0, stream>>>(x, Wcat, N, yq, z, nGemm,
                                                         srcv, dstv, epos, E, off, sidx);

    float* outF = (float*)d_out;
    float* outL = outF + N;
    k_gather<<<(N + 3) / 4, 256, 0, stream>>>(yq, z, off, cnt, sidx, bl, bres,
                                              wscore, bscore, wcrit, bcrit,
                                              rrs, alpha, N, outF, outL);
}

// Round 13
// 251.120 us; speedup vs baseline: 1.1889x; 1.0782x over previous
//
#include <hip/hip_runtime.h>
#include <math.h>

#define DIN 256
#define HDIM 128
#define NCRIT 10

typedef __bf16 bf16;
typedef bf16 bf16x8 __attribute__((ext_vector_type(8)));
typedef float f32x4 __attribute__((ext_vector_type(4)));
typedef float f32x2 __attribute__((ext_vector_type(2)));

static inline size_t alignup(size_t x, size_t a) { return (x + a - 1) & ~(a - 1); }

__device__ inline float bflo(unsigned v) { return __uint_as_float(v << 16); }
__device__ inline float bfhi(unsigned v) { return __uint_as_float(v & 0xffff0000u); }

__device__ inline bf16x8 cvt8(float4 v0, float4 v1) {
    bf16x8 w;
    w[0] = (bf16)v0.x; w[1] = (bf16)v0.y; w[2] = (bf16)v0.z; w[3] = (bf16)v0.w;
    w[4] = (bf16)v1.x; w[5] = (bf16)v1.y; w[6] = (bf16)v1.z; w[7] = (bf16)v1.w;
    return w;
}

__device__ inline unsigned char f32_fp8(float f) {
    return (unsigned char)(__builtin_amdgcn_cvt_pk_fp8_f32(f, f, 0, false) & 0xFF);
}

// ---------- k1: wconv (blocks [0,nW)) || hist (blocks [nW,...)) ----------
__global__ void k_histw(const int* __restrict__ dst, int E, int* __restrict__ cnt,
                        int* __restrict__ epos, int nW,
                        const float* __restrict__ Wl, const float* __restrict__ Wr,
                        const float* __restrict__ Wres, bf16* __restrict__ Wcat) {
    int t = threadIdx.x;
    if ((int)blockIdx.x < nW) {
        int base = (blockIdx.x * 256 + t) * 4;
        if (base >= 384 * 256) return;
        int r = base >> 8;
        int c = base & 255;
        const float* W = (r < 128) ? Wl : ((r < 256) ? Wr : Wres);
        float4 v = *(const float4*)&W[(size_t)(r & 127) * 256 + c];
        bf16* o = &Wcat[base];
        o[0] = (bf16)v.x; o[1] = (bf16)v.y; o[2] = (bf16)v.z; o[3] = (bf16)v.w;
    } else {
        int i = (blockIdx.x - nW) * 256 + t;
        if (i < E) epos[i] = atomicAdd(&cnt[dst[i]], 1);
    }
}

// ---------- k2: alloc (wave scan + atomic base) ----------
__global__ void k_alloc(const int* __restrict__ cnt, int n, int* __restrict__ off,
                        int* __restrict__ total) {
    int i = blockIdx.x * 256 + threadIdx.x;
    int lane = threadIdx.x & 63;
    int v = (i < n) ? cnt[i] : 0;
    int s = v;
    #pragma unroll
    for (int d = 1; d < 64; d <<= 1) {
        int t = __shfl_up(s, d, 64);
        if (lane >= d) s += t;
    }
    int excl = s - v;
    int wtot = __shfl(s, 63, 64);
    int base = 0;
    if (lane == 63) base = atomicAdd(total, wtot);
    base = __shfl(base, 63, 64);
    if (i < n) off[i] = base + excl;
}

// ---------- k3: gemm (blocks [0,nGemm), 512 thr, 8 waves) || scatter ----------
// gemm: [y|z] = x @ Wcat^T, BM=64 BN=384 BK=32; A LDS-dbuf, B per-frag from L2
// y stored fp8 e4m3 [node][128]; z bf16 [node][256]
__global__ __launch_bounds__(512) void k_gemsc(
    const float* __restrict__ x, const bf16* __restrict__ Wcat, int n,
    unsigned char* __restrict__ yq, bf16* __restrict__ z, int nGemm,
    const int* __restrict__ src, const int* __restrict__ dstv,
    const int* __restrict__ epos, int E,
    const int* __restrict__ off, int* __restrict__ sidx) {
    __shared__ __align__(16) char smem[43008];   // A dbuf 8KB aliased by epilogue 43KB
    int t = threadIdx.x;

    if ((int)blockIdx.x >= nGemm) {
        int i = ((int)blockIdx.x - nGemm) * 512 + t;
        if (i < E) sidx[off[dstv[i]] + epos[i]] = src[i];
        return;
    }

    int wv = t >> 6, lane = t & 63;
    int node0 = blockIdx.x * 64;
    int f_kg = lane >> 4, f_l15 = lane & 15;

    f32x4 acc[4][3] = {};

    // A staging (threads 0..255): row = t>>2, 16B chunk kq = t&3
    int a_r = t >> 2, a_kq = t & 3;
    int a_gr = node0 + a_r;
    const float* a_src = &x[(size_t)a_gr * DIN + a_kq * 8];
    int a_woff = a_kq * 1024 + ((a_r ^ (a_kq << 1)) << 4);
    bool a_do = (t < 256);

    // A fragment read offsets (swizzled)
    int aRd[4];
    #pragma unroll
    for (int m = 0; m < 4; m++) {
        int r = m * 16 + f_l15;
        aRd[m] = f_kg * 1024 + ((r ^ (f_kg << 1)) << 4);
    }

    // B fragment base: col = wv*48 + nn*16 + f_l15, k chunk = f_kg*8 + s*32
    const bf16* wb = Wcat + ((size_t)(wv * 48 + f_l15)) * DIN + (f_kg << 3);

    // prologue: stage A(0) into buf0; load B frags for s=0
    {
        float4 v0, v1;
        if (a_do) {
            if (a_gr < n) { v0 = *(const float4*)a_src; v1 = *(const float4*)(a_src + 4); }
            else { v0 = make_float4(0, 0, 0, 0); v1 = v0; }
            *(bf16x8*)(smem + a_woff) = cvt8(v0, v1);
        }
    }
    bf16x8 bfr[3];
    #pragma unroll
    for (int nn = 0; nn < 3; nn++)
        bfr[nn] = *(const bf16x8*)(wb + (size_t)nn * 16 * DIN);
    __syncthreads();

    #pragma unroll 2
    for (int s = 0; s < 8; ++s) {
        int cur = s & 1;
        float4 v0, v1;
        bf16x8 bnx[3];
        if (s < 7) {
            // issue next-step loads early (regs survive the barrier)
            if (a_do) {
                if (a_gr < n) {
                    v0 = *(const float4*)(a_src + (s + 1) * 32);
                    v1 = *(const float4*)(a_src + (s + 1) * 32 + 4);
                } else { v0 = make_float4(0, 0, 0, 0); v1 = v0; }
            }
            #pragma unroll
            for (int nn = 0; nn < 3; nn++)
                bnx[nn] = *(const bf16x8*)(wb + (size_t)nn * 16 * DIN + (s + 1) * 32);
        }
        bf16x8 afr[4];
        #pragma unroll
        for (int m = 0; m < 4; m++)
            afr[m] = *(const bf16x8*)(smem + cur * 4096 + aRd[m]);
        __builtin_amdgcn_s_setprio(1);
        #pragma unroll
        for (int m = 0; m < 4; m++)
            #pragma unroll
            for (int nn = 0; nn < 3; nn++)
                acc[m][nn] = __builtin_amdgcn_mfma_f32_16x16x32_bf16(
                    afr[m], bfr[nn], acc[m][nn], 0, 0, 0);
        __builtin_amdgcn_s_setprio(0);
        if (s < 7) {
            if (a_do)
                *(bf16x8*)(smem + (cur ^ 1) * 4096 + a_woff) = cvt8(v0, v1);
            #pragma unroll
            for (int nn = 0; nn < 3; nn++)
                bfr[nn] = bnx[nn];
        }
        __syncthreads();
    }

    // epilogue: y cols (0..127) -> fp8 region; z cols (128..383) -> bf16 region
    unsigned char* Cs8 = (unsigned char*)smem;     // [64][144] fp8
    bf16* Csz = (bf16*)(smem + 9216);              // [64][264] bf16
    #pragma unroll
    for (int m = 0; m < 4; m++) {
        #pragma unroll
        for (int nn = 0; nn < 3; nn++) {
            int col = wv * 48 + nn * 16 + f_l15;
            int r0 = m * 16 + (f_kg << 2);
            if (col < 128) {
                #pragma unroll
                for (int j = 0; j < 4; j++)
                    Cs8[(r0 + j) * 144 + col] = f32_fp8(acc[m][nn][j]);
            } else {
                #pragma unroll
                for (int j = 0; j < 4; j++)
                    Csz[(r0 + j) * 264 + (col - 128)] = (bf16)acc[m][nn][j];
            }
        }
    }
    __syncthreads();

    // y store: 64 rows x 128B fp8 (512 threads x 16B)
    {
        int r = t >> 3, ch = t & 7;
        int gr = node0 + r;
        if (gr < n) {
            uint4 v = *(const uint4*)&Cs8[r * 144 + ch * 16];
            *(uint4*)&yq[(size_t)gr * 128 + ch * 16] = v;
        }
    }
    // z store: 64 rows x 512B bf16 (512 threads x 4 x 16B)
    {
        int r = t >> 3;
        int gr = node0 + r;
        if (gr < n) {
            #pragma unroll
            for (int u = 0; u < 4; u++) {
                int c = ((t & 7) + u * 8) * 8;
                uint4 v = *(const uint4*)&Csz[r * 264 + c];
                *(uint4*)&z[(size_t)gr * 2 * HDIM + c] = v;
            }
        }
    }
}

// ---------- k4: fused gather + epilogue: one wave per node, fp8 rows, pk-cvt ----------
__global__ __launch_bounds__(256) void k_gather(
    const unsigned char* __restrict__ yq, const bf16* __restrict__ z,
    const int* __restrict__ off, const int* __restrict__ cnt, const int* __restrict__ sidx,
    const float* __restrict__ bl, const float* __restrict__ bres,
    const float* __restrict__ wscore, const float* __restrict__ bscore,
    const float* __restrict__ wcrit, const float* __restrict__ bcrit,
    const float* __restrict__ rrs, const float* __restrict__ palpha,
    int n, float* __restrict__ outF, float* __restrict__ outL)
{
    __shared__ bf16 wsb[11 * 128];
    int t = threadIdx.x;
    for (int i = t; i < 11 * 128; i += 256) {
        int q = i >> 7, c = i & 127;
        wsb[i] = (bf16)((q == 0) ? wscore[c] : wcrit[(size_t)(q - 1) * HDIM + c]);
    }
    __syncthreads();

    int node = blockIdx.x * 4 + (t >> 6);
    if (node >= n) return;
    int lane = t & 63, r2 = lane >> 5, c32 = lane & 31;

    // node-local loads issued early (hide under gather loop)
    uint2 zr = *(const uint2*)&z[(size_t)node * 2 * HDIM + c32 * 4];
    uint2 zs = *(const uint2*)&z[(size_t)node * 2 * HDIM + HDIM + c32 * 4];
    float4 blv = *(const float4*)&bl[c32 * 4];
    float4 brv = *(const float4*)&bres[c32 * 4];

    const unsigned char* ybase = yq + c32 * 4;
    int beg = off[node], len = cnt[node];
    const int* sp = sidx + beg;

    f32x2 a01 = {0.f, 0.f}, a23 = {0.f, 0.f};
    int e = 0;
    for (; e + 8 <= len; e += 8) {
        int i0 = sp[e + r2];
        int i1 = sp[e + 2 + r2];
        int i2 = sp[e + 4 + r2];
        int i3 = sp[e + 6 + r2];
        int v0 = *(const int*)(ybase + ((size_t)(unsigned)i0 << 7));
        int v1 = *(const int*)(ybase + ((size_t)(unsigned)i1 << 7));
        int v2 = *(const int*)(ybase + ((size_t)(unsigned)i2 << 7));
        int v3 = *(const int*)(ybase + ((size_t)(unsigned)i3 << 7));
        a01 += __builtin_amdgcn_cvt_pk_f32_fp8(v0, false)
             + __builtin_amdgcn_cvt_pk_f32_fp8(v1, false)
             + __builtin_amdgcn_cvt_pk_f32_fp8(v2, false)
             + __builtin_amdgcn_cvt_pk_f32_fp8(v3, false);
        a23 += __builtin_amdgcn_cvt_pk_f32_fp8(v0, true)
             + __builtin_amdgcn_cvt_pk_f32_fp8(v1, true)
             + __builtin_amdgcn_cvt_pk_f32_fp8(v2, true)
             + __builtin_amdgcn_cvt_pk_f32_fp8(v3, true);
    }
    for (; e < len; e += 2) {
        int slot = e + r2;
        int ii = sp[slot < len ? slot : len - 1];
        int v = *(const int*)(ybase + ((size_t)(unsigned)ii << 7));
        if (slot < len) {
            a01 += __builtin_amdgcn_cvt_pk_f32_fp8(v, false);
            a23 += __builtin_amdgcn_cvt_pk_f32_fp8(v, true);
        }
    }
    float a0 = a01[0], a1 = a01[1], a2 = a23[0], a3 = a23[1];
    a0 += __shfl_xor(a0, 32, 64);
    a1 += __shfl_xor(a1, 32, 64);
    a2 += __shfl_xor(a2, 32, 64);
    a3 += __shfl_xor(a3, 32, 64);
    float inv = 1.f / fmaxf((float)len, 1.f);

    float h0 = fmaxf(a0 * inv + blv.x + bflo(zr.x), 0.f) + bflo(zs.x) + brv.x;
    float h1 = fmaxf(a1 * inv + blv.y + bfhi(zr.x), 0.f) + bfhi(zs.x) + brv.y;
    float h2 = fmaxf(a2 * inv + blv.z + bflo(zr.y), 0.f) + bflo(zs.y) + brv.z;
    float h3 = fmaxf(a3 * inv + blv.w + bfhi(zr.y), 0.f) + bfhi(zs.y) + brv.w;

    // split epilogue: half r2=0 handles q=0..5, half r2=1 handles q=6..10
    float p[6];
    #pragma unroll
    for (int qq = 0; qq < 6; qq++) {
        int q = r2 * 6 + qq;
        float s = 0.f;
        if (q < 11) {
            uint2 w = *(const uint2*)&wsb[q * 128 + c32 * 4];
            s = h0 * bflo(w.x) + h1 * bfhi(w.x) + h2 * bflo(w.y) + h3 * bfhi(w.y);
        }
        #pragma unroll
        for (int d = 1; d < 32; d <<= 1)
            s += __shfl_xor(s, d, 64);
        p[qq] = s;
    }
    if ((lane & 31) == 0) {
        if (r2 == 0) {
            float al = palpha[0];
            float aa = 1.f / (1.f + expf(-al));
            outF[node] = aa * rrs[node] + (1.f - aa) * (p[0] + bscore[0]);
            #pragma unroll
            for (int qq = 1; qq < 6; qq++)
                outL[(size_t)node * NCRIT + qq - 1] = p[qq] + bcrit[qq - 1];
        } else {
            #pragma unroll
            for (int qq = 0; qq < 5; qq++)
                outL[(size_t)node * NCRIT + 5 + qq] = p[qq] + bcrit[5 + qq];
        }
    }
}

extern "C" void kernel_launch(void* const* d_in, const int* in_sizes, int n_in,
                              void* d_out, int out_size, void* d_ws, size_t ws_size,
                              hipStream_t stream) {
    const float* x      = (const float*)d_in[0];
    const int*   ei     = (const int*)d_in[1];
    const float* rrs    = (const float*)d_in[2];
    const float* Wl     = (const float*)d_in[3];
    const float* bl     = (const float*)d_in[4];
    const float* Wr     = (const float*)d_in[5];
    const float* Wres   = (const float*)d_in[6];
    const float* bres   = (const float*)d_in[7];
    const float* wscore = (const float*)d_in[8];
    const float* bscore = (const float*)d_in[9];
    const float* wcrit  = (const float*)d_in[10];
    const float* bcrit  = (const float*)d_in[11];
    const float* alpha  = (const float*)d_in[12];

    int N = in_sizes[0] / DIN;
    int E = in_sizes[1] / 2;
    const int* srcv = ei;
    const int* dstv = ei + E;

    char* p = (char*)d_ws;
    size_t cntPad = alignup((size_t)N * 4, 256);
    int* cnt   = (int*)p; p += cntPad;
    int* total = (int*)p; p += 256;
    int* off   = (int*)p; p += alignup((size_t)N * 4, 256);
    int* epos  = (int*)p; p += alignup((size_t)E * 4, 256);
    int* sidx  = (int*)p; p += alignup((size_t)E * 4, 256);
    bf16* Wcat = (bf16*)p; p += alignup((size_t)384 * DIN * 2, 256);
    unsigned char* yq = (unsigned char*)p; p += alignup((size_t)N * HDIM, 256);
    bf16* z    = (bf16*)p; p += alignup((size_t)N * 2 * HDIM * 2, 256);

    // single memset covers cnt + total (adjacent)
    hipMemsetAsync(cnt, 0, cntPad + 256, stream);

    int nW = 96;   // wconv blocks
    k_histw<<<nW + (E + 255) / 256, 256, 0, stream>>>(dstv, E, cnt, epos, nW,
                                                      Wl, Wr, Wres, Wcat);
    k_alloc<<<(N + 255) / 256, 256, 0, stream>>>(cnt, N, off, total);

    int nGemm = (N + 63) / 64;
    k_gemsc<<<nGemm + (E + 511) / 512, 512, 0, stream>>>(x, Wcat, N, yq, z, nGemm,
                                                         srcv, dstv, epos, E, off, sidx);

    float* outF = (float*)d_out;
    float* outL = outF + N;
    k_gather<<<(N + 3) / 4, 256, 0, stream>>>(yq, z, off, cnt, sidx, bl, bres,
                                              wscore, bscore, wcrit, bcrit,
                                              rrs, alpha, N, outF, outL);
}

// Round 14
// 249.218 us; speedup vs baseline: 1.1980x; 1.0076x over previous
//
#include <hip/hip_runtime.h>
#include <math.h>

#define DIN 256
#define HDIM 128
#define NCRIT 10

typedef __bf16 bf16;
typedef bf16 bf16x8 __attribute__((ext_vector_type(8)));
typedef float f32x4 __attribute__((ext_vector_type(4)));
typedef float f32x2 __attribute__((ext_vector_type(2)));

static inline size_t alignup(size_t x, size_t a) { return (x + a - 1) & ~(a - 1); }

__device__ inline float bflo(unsigned v) { return __uint_as_float(v << 16); }
__device__ inline float bfhi(unsigned v) { return __uint_as_float(v & 0xffff0000u); }

__device__ inline bf16x8 cvt8(float4 v0, float4 v1) {
    bf16x8 w;
    w[0] = (bf16)v0.x; w[1] = (bf16)v0.y; w[2] = (bf16)v0.z; w[3] = (bf16)v0.w;
    w[4] = (bf16)v1.x; w[5] = (bf16)v1.y; w[6] = (bf16)v1.z; w[7] = (bf16)v1.w;
    return w;
}

__device__ inline unsigned char f32_fp8(float f) {
    return (unsigned char)(__builtin_amdgcn_cvt_pk_fp8_f32(f, f, 0, false) & 0xFF);
}

// ---------- k1: wconv + Wcomb + zero-pad (blocks [0,108)) || hist (blocks [108,...)) ----------
// Wcat rows: 0..127 = Wl, 128..255 = Wr, 256..266 = Wepi@Wres, 267..383 = 0
__global__ void k_histw(const int* __restrict__ dst, int E, int* __restrict__ cnt,
                        int* __restrict__ epos, int nW,
                        const float* __restrict__ Wl, const float* __restrict__ Wr,
                        const float* __restrict__ Wres,
                        const float* __restrict__ wscore, const float* __restrict__ wcrit,
                        bf16* __restrict__ Wcat) {
    int t = threadIdx.x;
    int b = blockIdx.x;
    if (b < 64) {
        // Wl / Wr rows 0..255
        int base = (b * 256 + t) * 4;
        int r = base >> 8;
        int c = base & 255;
        const float* W = (r < 128) ? Wl : Wr;
        float4 v = *(const float4*)&W[(size_t)(r & 127) * 256 + c];
        bf16* o = &Wcat[base];
        o[0] = (bf16)v.x; o[1] = (bf16)v.y; o[2] = (bf16)v.z; o[3] = (bf16)v.w;
    } else if (b < 80) {
        // Wcomb rows 256..271: q = b-64 (one per block), k = t
        int q = b - 64;
        int k = t;
        float s = 0.f;
        if (q < 11) {
            const float* wepi = (q == 0) ? wscore : &wcrit[(size_t)(q - 1) * HDIM];
            for (int c = 0; c < HDIM; ++c)
                s += wepi[c] * Wres[(size_t)c * 256 + k];
        }
        Wcat[(size_t)(256 + q) * 256 + k] = (bf16)s;
    } else if (b < 108) {
        // zero rows 272..383 (28 blocks x 256 thr x 4 elems = 28672 elems)
        int base = 272 * 256 + ((b - 80) * 256 + t) * 4;
        bf16* o = &Wcat[base];
        o[0] = (bf16)0.f; o[1] = (bf16)0.f; o[2] = (bf16)0.f; o[3] = (bf16)0.f;
    } else {
        int i = (b - nW) * 256 + t;
        if (i < E) epos[i] = atomicAdd(&cnt[dst[i]], 1);
    }
}

// ---------- k2: alloc (wave scan + atomic base) ----------
__global__ void k_alloc(const int* __restrict__ cnt, int n, int* __restrict__ off,
                        int* __restrict__ total) {
    int i = blockIdx.x * 256 + threadIdx.x;
    int lane = threadIdx.x & 63;
    int v = (i < n) ? cnt[i] : 0;
    int s = v;
    #pragma unroll
    for (int d = 1; d < 64; d <<= 1) {
        int t = __shfl_up(s, d, 64);
        if (lane >= d) s += t;
    }
    int excl = s - v;
    int wtot = __shfl(s, 63, 64);
    int base = 0;
    if (lane == 63) base = atomicAdd(total, wtot);
    base = __shfl(base, 63, 64);
    if (i < n) off[i] = base + excl;
}

// ---------- k3: gemm (blocks [0,nGemm), 512 thr) || scatter ----------
// gemm: [y | zr | w] = x @ Wcat^T; BM=64, BN=272(+pad), BK=32
// y fp8 [node][128]; zr bf16 [node][128]; w f32 [node][16] (Wepi@Wres@x)
__global__ __launch_bounds__(512) void k_gemsc(
    const float* __restrict__ x, const bf16* __restrict__ Wcat, int n,
    unsigned char* __restrict__ yq, bf16* __restrict__ z, float* __restrict__ w,
    int nGemm,
    const int* __restrict__ src, const int* __restrict__ dstv,
    const int* __restrict__ epos, int E,
    const int* __restrict__ off, int* __restrict__ sidx) {
    __shared__ __align__(16) char smem[26624];   // A dbuf 8KB aliased by epilogue
    int t = threadIdx.x;

    if ((int)blockIdx.x >= nGemm) {
        int i = ((int)blockIdx.x - nGemm) * 512 + t;
        if (i < E) sidx[off[dstv[i]] + epos[i]] = src[i];
        return;
    }

    int wv = t >> 6, lane = t & 63;
    int node0 = blockIdx.x * 64;
    int f_kg = lane >> 4, f_l15 = lane & 15;

    f32x4 acc[4][3] = {};

    // A staging (threads 0..255): row = t>>2, 16B chunk kq = t&3
    int a_r = t >> 2, a_kq = t & 3;
    int a_gr = node0 + a_r;
    const float* a_src = &x[(size_t)a_gr * DIN + a_kq * 8];
    int a_woff = a_kq * 1024 + ((a_r ^ (a_kq << 1)) << 4);
    bool a_do = (t < 256);

    int aRd[4];
    #pragma unroll
    for (int m = 0; m < 4; m++) {
        int r = m * 16 + f_l15;
        aRd[m] = f_kg * 1024 + ((r ^ (f_kg << 1)) << 4);
    }

    // B bases: nn<2 -> col = wv*32 + nn*16 + f_l15; nn=2 -> col = 256 + wv*16 + f_l15
    const bf16* wb01 = Wcat + ((size_t)(wv * 32 + f_l15)) * DIN + (f_kg << 3);
    const bf16* wb2  = Wcat + ((size_t)(256 + wv * 16 + f_l15)) * DIN + (f_kg << 3);

    // prologue
    {
        float4 v0, v1;
        if (a_do) {
            if (a_gr < n) { v0 = *(const float4*)a_src; v1 = *(const float4*)(a_src + 4); }
            else { v0 = make_float4(0, 0, 0, 0); v1 = v0; }
            *(bf16x8*)(smem + a_woff) = cvt8(v0, v1);
        }
    }
    bf16x8 bfr[3];
    bfr[0] = *(const bf16x8*)wb01;
    bfr[1] = *(const bf16x8*)(wb01 + (size_t)16 * DIN);
    bfr[2] = *(const bf16x8*)wb2;
    __syncthreads();

    #pragma unroll 2
    for (int s = 0; s < 8; ++s) {
        int cur = s & 1;
        float4 v0, v1;
        bf16x8 bnx[3];
        if (s < 7) {
            if (a_do) {
                if (a_gr < n) {
                    v0 = *(const float4*)(a_src + (s + 1) * 32);
                    v1 = *(const float4*)(a_src + (s + 1) * 32 + 4);
                } else { v0 = make_float4(0, 0, 0, 0); v1 = v0; }
            }
            bnx[0] = *(const bf16x8*)(wb01 + (s + 1) * 32);
            bnx[1] = *(const bf16x8*)(wb01 + (size_t)16 * DIN + (s + 1) * 32);
            bnx[2] = *(const bf16x8*)(wb2 + (s + 1) * 32);
        }
        bf16x8 afr[4];
        #pragma unroll
        for (int m = 0; m < 4; m++)
            afr[m] = *(const bf16x8*)(smem + cur * 4096 + aRd[m]);
        __builtin_amdgcn_s_setprio(1);
        #pragma unroll
        for (int m = 0; m < 4; m++)
            #pragma unroll
            for (int nn = 0; nn < 3; nn++)
                acc[m][nn] = __builtin_amdgcn_mfma_f32_16x16x32_bf16(
                    afr[m], bfr[nn], acc[m][nn], 0, 0, 0);
        __builtin_amdgcn_s_setprio(0);
        if (s < 7) {
            if (a_do)
                *(bf16x8*)(smem + (cur ^ 1) * 4096 + a_woff) = cvt8(v0, v1);
            bfr[0] = bnx[0]; bfr[1] = bnx[1]; bfr[2] = bnx[2];
        }
        __syncthreads();
    }

    // epilogue: cols 0..127 -> fp8 y; 128..255 -> bf16 zr; wv0 nn2 -> w f32 direct
    unsigned char* Cs8 = (unsigned char*)smem;     // [64][144] fp8
    bf16* Csz = (bf16*)(smem + 9216);              // [64][136] bf16
    #pragma unroll
    for (int m = 0; m < 4; m++) {
        #pragma unroll
        for (int nn = 0; nn < 2; nn++) {
            int col = wv * 32 + nn * 16 + f_l15;
            int r0 = m * 16 + (f_kg << 2);
            if (col < 128) {
                #pragma unroll
                for (int j = 0; j < 4; j++)
                    Cs8[(r0 + j) * 144 + col] = f32_fp8(acc[m][nn][j]);
            } else {
                #pragma unroll
                for (int j = 0; j < 4; j++)
                    Csz[(r0 + j) * 136 + (col - 128)] = (bf16)acc[m][nn][j];
            }
        }
    }
    if (wv == 0) {
        #pragma unroll
        for (int m = 0; m < 4; m++) {
            int r0 = m * 16 + (f_kg << 2);
            #pragma unroll
            for (int j = 0; j < 4; j++) {
                int gr = node0 + r0 + j;
                if (gr < n) w[(size_t)gr * 16 + f_l15] = acc[m][2][j];
            }
        }
    }
    __syncthreads();

    // y store: 64 rows x 128B fp8 (512 threads x 16B)
    {
        int r = t >> 3, ch = t & 7;
        int gr = node0 + r;
        if (gr < n) {
            uint4 v = *(const uint4*)&Cs8[r * 144 + ch * 16];
            *(uint4*)&yq[(size_t)gr * 128 + ch * 16] = v;
        }
    }
    // zr store: 64 rows x 256B bf16 (512 threads x 32B)
    {
        int r = t >> 3, ch = t & 7;
        int gr = node0 + r;
        if (gr < n) {
            uint4 v0 = *(const uint4*)&Csz[r * 136 + ch * 16];
            uint4 v1 = *(const uint4*)&Csz[r * 136 + ch * 16 + 8];
            *(uint4*)&z[(size_t)gr * HDIM + ch * 16] = v0;
            *(uint4*)&z[(size_t)gr * HDIM + ch * 16 + 8] = v1;
        }
    }
}

// ---------- k4: fused gather + epilogue ----------
__global__ __launch_bounds__(256) void k_gather(
    const unsigned char* __restrict__ yq, const bf16* __restrict__ z,
    const float* __restrict__ w,
    const int* __restrict__ off, const int* __restrict__ cnt, const int* __restrict__ sidx,
    const float* __restrict__ bl, const float* __restrict__ bres,
    const float* __restrict__ wscore, const float* __restrict__ bscore,
    const float* __restrict__ wcrit, const float* __restrict__ bcrit,
    const float* __restrict__ rrs, const float* __restrict__ palpha,
    int n, float* __restrict__ outF, float* __restrict__ outL)
{
    __shared__ bf16 wsb[11 * 128];
    int t = threadIdx.x;
    for (int i = t; i < 11 * 128; i += 256) {
        int q = i >> 7, c = i & 127;
        wsb[i] = (bf16)((q == 0) ? wscore[c] : wcrit[(size_t)(q - 1) * HDIM + c]);
    }
    __syncthreads();

    int node = blockIdx.x * 4 + (t >> 6);
    if (node >= n) return;
    int lane = t & 63, r2 = lane >> 5, c32 = lane & 31;

    // node-local loads issued early (hide under gather loop)
    uint2 zr = *(const uint2*)&z[(size_t)node * HDIM + c32 * 4];
    float wpre = (lane < 16) ? w[(size_t)node * 16 + lane] : 0.f;
    float4 blv = *(const float4*)&bl[c32 * 4];
    float4 brv = *(const float4*)&bres[c32 * 4];

    const unsigned char* ybase = yq + c32 * 4;
    int beg = off[node], len = cnt[node];
    const int* sp = sidx + beg;

    f32x2 a01 = {0.f, 0.f}, a23 = {0.f, 0.f};
    int e = 0;
    for (; e + 8 <= len; e += 8) {
        int i0 = sp[e + r2];
        int i1 = sp[e + 2 + r2];
        int i2 = sp[e + 4 + r2];
        int i3 = sp[e + 6 + r2];
        int v0 = *(const int*)(ybase + ((size_t)(unsigned)i0 << 7));
        int v1 = *(const int*)(ybase + ((size_t)(unsigned)i1 << 7));
        int v2 = *(const int*)(ybase + ((size_t)(unsigned)i2 << 7));
        int v3 = *(const int*)(ybase + ((size_t)(unsigned)i3 << 7));
        a01 += __builtin_amdgcn_cvt_pk_f32_fp8(v0, false)
             + __builtin_amdgcn_cvt_pk_f32_fp8(v1, false)
             + __builtin_amdgcn_cvt_pk_f32_fp8(v2, false)
             + __builtin_amdgcn_cvt_pk_f32_fp8(v3, false);
        a23 += __builtin_amdgcn_cvt_pk_f32_fp8(v0, true)
             + __builtin_amdgcn_cvt_pk_f32_fp8(v1, true)
             + __builtin_amdgcn_cvt_pk_f32_fp8(v2, true)
             + __builtin_amdgcn_cvt_pk_f32_fp8(v3, true);
    }
    for (; e < len; e += 2) {
        int slot = e + r2;
        int ii = sp[slot < len ? slot : len - 1];
        int v = *(const int*)(ybase + ((size_t)(unsigned)ii << 7));
        if (slot < len) {
            a01 += __builtin_amdgcn_cvt_pk_f32_fp8(v, false);
            a23 += __builtin_amdgcn_cvt_pk_f32_fp8(v, true);
        }
    }
    float a0 = a01[0], a1 = a01[1], a2 = a23[0], a3 = a23[1];
    a0 += __shfl_xor(a0, 32, 64);
    a1 += __shfl_xor(a1, 32, 64);
    a2 += __shfl_xor(a2, 32, 64);
    a3 += __shfl_xor(a3, 32, 64);
    float inv = 1.f / fmaxf((float)len, 1.f);

    // h' = relu(agg + bl + zr) + bres  (Wres/bres contribution folded into w + dot(bres))
    float h0 = fmaxf(a0 * inv + blv.x + bflo(zr.x), 0.f) + brv.x;
    float h1 = fmaxf(a1 * inv + blv.y + bfhi(zr.x), 0.f) + brv.y;
    float h2 = fmaxf(a2 * inv + blv.z + bflo(zr.y), 0.f) + brv.z;
    float h3 = fmaxf(a3 * inv + blv.w + bfhi(zr.y), 0.f) + brv.w;

    // split epilogue: r2=0 -> q=0..5, r2=1 -> q=6..10
    float p[6], wq[6];
    #pragma unroll
    for (int qq = 0; qq < 6; qq++) {
        int q = r2 * 6 + qq;
        float s = 0.f;
        if (q < 11) {
            uint2 ww = *(const uint2*)&wsb[q * 128 + c32 * 4];
            s = h0 * bflo(ww.x) + h1 * bfhi(ww.x) + h2 * bflo(ww.y) + h3 * bfhi(ww.y);
        }
        #pragma unroll
        for (int d = 1; d < 32; d <<= 1)
            s += __shfl_xor(s, d, 64);
        p[qq] = s;
        wq[qq] = __shfl(wpre, (q < 11) ? q : 0, 64);
    }
    if ((lane & 31) == 0) {
        if (r2 == 0) {
            float al = palpha[0];
            float aa = 1.f / (1.f + expf(-al));
            outF[node] = aa * rrs[node] + (1.f - aa) * (p[0] + wq[0] + bscore[0]);
            #pragma unroll
            for (int qq = 1; qq < 6; qq++)
                outL[(size_t)node * NCRIT + qq - 1] = p[qq] + wq[qq] + bcrit[qq - 1];
        } else {
            #pragma unroll
            for (int qq = 0; qq < 5; qq++)
                outL[(size_t)node * NCRIT + 5 + qq] = p[qq] + wq[qq] + bcrit[5 + qq];
        }
    }
}

extern "C" void kernel_launch(void* const* d_in, const int* in_sizes, int n_in,
                              void* d_out, int out_size, void* d_ws, size_t ws_size,
                              hipStream_t stream) {
    const float* x      = (const float*)d_in[0];
    const int*   ei     = (const int*)d_in[1];
    const float* rrs    = (const float*)d_in[2];
    const float* Wl     = (const float*)d_in[3];
    const float* bl     = (const float*)d_in[4];
    const float* Wr     = (const float*)d_in[5];
    const float* Wres   = (const float*)d_in[6];
    const float* bres   = (const float*)d_in[7];
    const float* wscore = (const float*)d_in[8];
    const float* bscore = (const float*)d_in[9];
    const float* wcrit  = (const float*)d_in[10];
    const float* bcrit  = (const float*)d_in[11];
    const float* alpha  = (const float*)d_in[12];

    int N = in_sizes[0] / DIN;
    int E = in_sizes[1] / 2;
    const int* srcv = ei;
    const int* dstv = ei + E;

    char* p = (char*)d_ws;
    size_t cntPad = alignup((size_t)N * 4, 256);
    int* cnt   = (int*)p; p += cntPad;
    int* total = (int*)p; p += 256;
    int* off   = (int*)p; p += alignup((size_t)N * 4, 256);
    int* epos  = (int*)p; p += alignup((size_t)E * 4, 256);
    int* sidx  = (int*)p; p += alignup((size_t)E * 4, 256);
    bf16* Wcat = (bf16*)p; p += alignup((size_t)384 * DIN * 2, 256);
    unsigned char* yq = (unsigned char*)p; p += alignup((size_t)N * HDIM, 256);
    bf16* z    = (bf16*)p; p += alignup((size_t)N * HDIM * 2, 256);
    float* w   = (float*)p; p += alignup((size_t)N * 16 * 4, 256);

    // single memset covers cnt + total (adjacent)
    hipMemsetAsync(cnt, 0, cntPad + 256, stream);

    int nW = 108;   // 64 wconv + 16 Wcomb + 28 zero-pad
    k_histw<<<nW + (E + 255) / 256, 256, 0, stream>>>(dstv, E, cnt, epos, nW,
                                                      Wl, Wr, Wres, wscore, wcrit, Wcat);
    k_alloc<<<(N + 255) / 256, 256, 0, stream>>>(cnt, N, off, total);

    int nGemm = (N + 63) / 64;
    k_gemsc<<<nGemm + (E + 511) / 512, 512, 0, stream>>>(x, Wcat, N, yq, z, w, nGemm,
                                                         srcv, dstv, epos, E, off, sidx);

    float* outF = (float*)d_out;
    float* outL = outF + N;
    k_gather<<<(N + 3) / 4, 256, 0, stream>>>(yq, z, w, off, cnt, sidx, bl, bres,
                                              wscore, bscore, wcrit, bcrit,
                                              rrs, alpha, N, outF, outL);
}

// Round 15
// 242.783 us; speedup vs baseline: 1.2297x; 1.0265x over previous
//
#include <hip/hip_runtime.h>
#include <math.h>

#define DIN 256
#define HDIM 128
#define NCRIT 10

typedef __bf16 bf16;
typedef bf16 bf16x8 __attribute__((ext_vector_type(8)));
typedef float f32x4 __attribute__((ext_vector_type(4)));
typedef float f32x2 __attribute__((ext_vector_type(2)));

static inline size_t alignup(size_t x, size_t a) { return (x + a - 1) & ~(a - 1); }

__device__ inline float bflo(unsigned v) { return __uint_as_float(v << 16); }
__device__ inline float bfhi(unsigned v) { return __uint_as_float(v & 0xffff0000u); }

__device__ inline bf16x8 cvt8(float4 v0, float4 v1) {
    bf16x8 w;
    w[0] = (bf16)v0.x; w[1] = (bf16)v0.y; w[2] = (bf16)v0.z; w[3] = (bf16)v0.w;
    w[4] = (bf16)v1.x; w[5] = (bf16)v1.y; w[6] = (bf16)v1.z; w[7] = (bf16)v1.w;
    return w;
}

// ---------- k1: wconv rows 0..255 + Wcomb rows 256..271 (blocks [0,80)) || hist ----------
// Wcat rows: 0..127 = Wl, 128..255 = Wr, 256..266 = Wepi@Wres, 267..271 = 0
__global__ void k_histw(const int* __restrict__ dst, int E, int* __restrict__ cnt,
                        int* __restrict__ epos, int nW,
                        const float* __restrict__ Wl, const float* __restrict__ Wr,
                        const float* __restrict__ Wres,
                        const float* __restrict__ wscore, const float* __restrict__ wcrit,
                        bf16* __restrict__ Wcat) {
    int t = threadIdx.x;
    int b = blockIdx.x;
    if (b < 64) {
        int base = (b * 256 + t) * 4;
        int r = base >> 8;
        int c = base & 255;
        const float* W = (r < 128) ? Wl : Wr;
        float4 v = *(const float4*)&W[(size_t)(r & 127) * 256 + c];
        bf16* o = &Wcat[base];
        o[0] = (bf16)v.x; o[1] = (bf16)v.y; o[2] = (bf16)v.z; o[3] = (bf16)v.w;
    } else if (b < 80) {
        int q = b - 64;
        int k = t;
        float s = 0.f;
        if (q < 11) {
            const float* wepi = (q == 0) ? wscore : &wcrit[(size_t)(q - 1) * HDIM];
            for (int c = 0; c < HDIM; ++c)
                s += wepi[c] * Wres[(size_t)c * 256 + k];
        }
        Wcat[(size_t)(256 + q) * 256 + k] = (bf16)s;
    } else {
        int i = (b - nW) * 256 + t;
        if (i < E) epos[i] = atomicAdd(&cnt[dst[i]], 1);
    }
}

// ---------- k2: alloc (wave scan + atomic base) ----------
__global__ void k_alloc(const int* __restrict__ cnt, int n, int* __restrict__ off,
                        int* __restrict__ total) {
    int i = blockIdx.x * 256 + threadIdx.x;
    int lane = threadIdx.x & 63;
    int v = (i < n) ? cnt[i] : 0;
    int s = v;
    #pragma unroll
    for (int d = 1; d < 64; d <<= 1) {
        int t = __shfl_up(s, d, 64);
        if (lane >= d) s += t;
    }
    int excl = s - v;
    int wtot = __shfl(s, 63, 64);
    int base = 0;
    if (lane == 63) base = atomicAdd(total, wtot);
    base = __shfl(base, 63, 64);
    if (i < n) off[i] = base + excl;
}

// ---------- k3: barrier-free GEMM (B fully in LDS) + scatter tail ----------
// [y | zr | w] = x @ Wcat^T (272 cols); per wave: independent 16-row tile.
// B LDS layout: [skg 0..31][c 0..271][16B], skg = s*4+kg, k-offset = skg*8
// y fp8 [node][128]; zr bf16 [node][128]; w f32 [node][16]
__global__ __launch_bounds__(512) void k_gemm(
    const float* __restrict__ x, const bf16* __restrict__ Wcat, int n,
    unsigned char* __restrict__ yq, bf16* __restrict__ z, float* __restrict__ w,
    const int* __restrict__ src, const int* __restrict__ dstv,
    const int* __restrict__ epos, int E,
    const int* __restrict__ off, int* __restrict__ sidx)
{
    __shared__ __align__(16) char smem[147456];   // 136KB B + 8KB wave scratch
    int t = threadIdx.x;
    int wv = t >> 6, lane = t & 63;

    // stage B once: 8704 chunks of 16B, 17 per thread
    #pragma unroll
    for (int i = 0; i < 17; i++) {
        int idx = i * 512 + t;
        int c = idx >> 5, skg = idx & 31;
        *(bf16x8*)(smem + (((size_t)skg * 272 + c) << 4)) =
            *(const bf16x8*)(Wcat + (size_t)c * 256 + skg * 8);
    }
    __syncthreads();   // the only block-wide barrier

    int l15 = lane & 15, kq = lane >> 4;
    char* scr = smem + 139264 + wv * 1024;   // per-wave private scratch (16x16 f32)
    int rrow = lane >> 2, rc4 = (lane & 3) * 4;

    int nTiles = (n + 127) >> 7;
    for (int tile = blockIdx.x; tile < nTiles; tile += gridDim.x) {
        int rowb = tile * 128 + wv * 16;
        int myrow = rowb + l15;
        const float* ap = x + (size_t)(myrow < n ? myrow : (n - 1)) * 256 + kq * 8;

        f32x4 acc[17];
        #pragma unroll
        for (int C = 0; C < 17; C++) acc[C] = (f32x4){0.f, 0.f, 0.f, 0.f};

        #pragma unroll
        for (int s = 0; s < 8; s++) {
            float4 v0 = *(const float4*)(ap + s * 32);
            float4 v1 = *(const float4*)(ap + s * 32 + 4);
            bf16x8 afr = cvt8(v0, v1);
            int sbase = ((s * 4 + kq) * 272 + l15) << 4;
            #pragma unroll
            for (int C = 0; C < 17; C++) {
                bf16x8 b = *(const bf16x8*)(smem + sbase + C * 256);
                acc[C] = __builtin_amdgcn_mfma_f32_16x16x32_bf16(afr, b, acc[C], 0, 0, 0);
            }
        }

        // epilogue via per-wave scratch (no barriers; in-wave lgkm deps only)
        int gr = rowb + rrow;
        bool ok = gr < n;
        #pragma unroll
        for (int C = 0; C < 17; C++) {
            #pragma unroll
            for (int j = 0; j < 4; j++)
                *(float*)(scr + ((((kq << 2) + j) * 16 + l15) << 2)) = acc[C][j];
            f32x4 vv = *(const f32x4*)(scr + ((rrow * 16 + rc4) << 2));
            if (C < 8) {
                unsigned pk = (unsigned)__builtin_amdgcn_cvt_pk_fp8_f32(vv[0], vv[1], 0, false);
                pk = (unsigned)__builtin_amdgcn_cvt_pk_fp8_f32(vv[2], vv[3], pk, true);
                if (ok) *(unsigned*)(yq + (size_t)gr * 128 + C * 16 + rc4) = pk;
            } else if (C < 16) {
                bf16 o[4] = {(bf16)vv[0], (bf16)vv[1], (bf16)vv[2], (bf16)vv[3]};
                if (ok) *(uint2*)((char*)z + (size_t)gr * 256 + (C - 8) * 32 + rc4 * 2) =
                            *(const uint2*)o;
            } else {
                if (ok) *(f32x4*)(w + (size_t)gr * 16 + rc4) = vv;
            }
        }
    }

    // scatter tail (grid-stride; overlaps gemm tail imbalance)
    for (int i = blockIdx.x * 512 + t; i < E; i += gridDim.x * 512)
        sidx[off[dstv[i]] + epos[i]] = src[i];
}

// ---------- k4: fused gather + epilogue ----------
__global__ __launch_bounds__(256) void k_gather(
    const unsigned char* __restrict__ yq, const bf16* __restrict__ z,
    const float* __restrict__ w,
    const int* __restrict__ off, const int* __restrict__ cnt, const int* __restrict__ sidx,
    const float* __restrict__ bl, const float* __restrict__ bres,
    const float* __restrict__ wscore, const float* __restrict__ bscore,
    const float* __restrict__ wcrit, const float* __restrict__ bcrit,
    const float* __restrict__ rrs, const float* __restrict__ palpha,
    int n, float* __restrict__ outF, float* __restrict__ outL)
{
    __shared__ bf16 wsb[11 * 128];
    int t = threadIdx.x;
    for (int i = t; i < 11 * 128; i += 256) {
        int q = i >> 7, c = i & 127;
        wsb[i] = (bf16)((q == 0) ? wscore[c] : wcrit[(size_t)(q - 1) * HDIM + c]);
    }
    __syncthreads();

    int node = blockIdx.x * 4 + (t >> 6);
    if (node >= n) return;
    int lane = t & 63, r2 = lane >> 5, c32 = lane & 31;

    uint2 zr = *(const uint2*)&z[(size_t)node * HDIM + c32 * 4];
    float wpre = (lane < 16) ? w[(size_t)node * 16 + lane] : 0.f;
    float4 blv = *(const float4*)&bl[c32 * 4];
    float4 brv = *(const float4*)&bres[c32 * 4];

    const unsigned char* ybase = yq + c32 * 4;
    int beg = off[node], len = cnt[node];
    const int* sp = sidx + beg;

    f32x2 a01 = {0.f, 0.f}, a23 = {0.f, 0.f};
    int e = 0;
    for (; e + 8 <= len; e += 8) {
        int i0 = sp[e + r2];
        int i1 = sp[e + 2 + r2];
        int i2 = sp[e + 4 + r2];
        int i3 = sp[e + 6 + r2];
        int v0 = *(const int*)(ybase + ((size_t)(unsigned)i0 << 7));
        int v1 = *(const int*)(ybase + ((size_t)(unsigned)i1 << 7));
        int v2 = *(const int*)(ybase + ((size_t)(unsigned)i2 << 7));
        int v3 = *(const int*)(ybase + ((size_t)(unsigned)i3 << 7));
        a01 += __builtin_amdgcn_cvt_pk_f32_fp8(v0, false)
             + __builtin_amdgcn_cvt_pk_f32_fp8(v1, false)
             + __builtin_amdgcn_cvt_pk_f32_fp8(v2, false)
             + __builtin_amdgcn_cvt_pk_f32_fp8(v3, false);
        a23 += __builtin_amdgcn_cvt_pk_f32_fp8(v0, true)
             + __builtin_amdgcn_cvt_pk_f32_fp8(v1, true)
             + __builtin_amdgcn_cvt_pk_f32_fp8(v2, true)
             + __builtin_amdgcn_cvt_pk_f32_fp8(v3, true);
    }
    for (; e < len; e += 2) {
        int slot = e + r2;
        int ii = sp[slot < len ? slot : len - 1];
        int v = *(const int*)(ybase + ((size_t)(unsigned)ii << 7));
        if (slot < len) {
            a01 += __builtin_amdgcn_cvt_pk_f32_fp8(v, false);
            a23 += __builtin_amdgcn_cvt_pk_f32_fp8(v, true);
        }
    }
    float a0 = a01[0], a1 = a01[1], a2 = a23[0], a3 = a23[1];
    a0 += __shfl_xor(a0, 32, 64);
    a1 += __shfl_xor(a1, 32, 64);
    a2 += __shfl_xor(a2, 32, 64);
    a3 += __shfl_xor(a3, 32, 64);
    float inv = 1.f / fmaxf((float)len, 1.f);

    // h' = relu(agg + bl + zr) + bres (Wres path folded into w; dot(bres) via brv here)
    float h0 = fmaxf(a0 * inv + blv.x + bflo(zr.x), 0.f) + brv.x;
    float h1 = fmaxf(a1 * inv + blv.y + bfhi(zr.x), 0.f) + brv.y;
    float h2 = fmaxf(a2 * inv + blv.z + bflo(zr.y), 0.f) + brv.z;
    float h3 = fmaxf(a3 * inv + blv.w + bfhi(zr.y), 0.f) + brv.w;

    float p[6], wq[6];
    #pragma unroll
    for (int qq = 0; qq < 6; qq++) {
        int q = r2 * 6 + qq;
        float s = 0.f;
        if (q < 11) {
            uint2 ww = *(const uint2*)&wsb[q * 128 + c32 * 4];
            s = h0 * bflo(ww.x) + h1 * bfhi(ww.x) + h2 * bflo(ww.y) + h3 * bfhi(ww.y);
        }
        #pragma unroll
        for (int d = 1; d < 32; d <<= 1)
            s += __shfl_xor(s, d, 64);
        p[qq] = s;
        wq[qq] = __shfl(wpre, (q < 11) ? q : 0, 64);
    }
    if ((lane & 31) == 0) {
        if (r2 == 0) {
            float al = palpha[0];
            float aa = 1.f / (1.f + expf(-al));
            outF[node] = aa * rrs[node] + (1.f - aa) * (p[0] + wq[0] + bscore[0]);
            #pragma unroll
            for (int qq = 1; qq < 6; qq++)
                outL[(size_t)node * NCRIT + qq - 1] = p[qq] + wq[qq] + bcrit[qq - 1];
        } else {
            #pragma unroll
            for (int qq = 0; qq < 5; qq++)
                outL[(size_t)node * NCRIT + 5 + qq] = p[qq] + wq[qq] + bcrit[5 + qq];
        }
    }
}

extern "C" void kernel_launch(void* const* d_in, const int* in_sizes, int n_in,
                              void* d_out, int out_size, void* d_ws, size_t ws_size,
                              hipStream_t stream) {
    const float* x      = (const float*)d_in[0];
    const int*   ei     = (const int*)d_in[1];
    const float* rrs    = (const float*)d_in[2];
    const float* Wl     = (const float*)d_in[3];
    const float* bl     = (const float*)d_in[4];
    const float* Wr     = (const float*)d_in[5];
    const float* Wres   = (const float*)d_in[6];
    const float* bres   = (const float*)d_in[7];
    const float* wscore = (const float*)d_in[8];
    const float* bscore = (const float*)d_in[9];
    const float* wcrit  = (const float*)d_in[10];
    const float* bcrit  = (const float*)d_in[11];
    const float* alpha  = (const float*)d_in[12];

    int N = in_sizes[0] / DIN;
    int E = in_sizes[1] / 2;
    const int* srcv = ei;
    const int* dstv = ei + E;

    char* p = (char*)d_ws;
    size_t cntPad = alignup((size_t)N * 4, 256);
    int* cnt   = (int*)p; p += cntPad;
    int* total = (int*)p; p += 256;
    int* off   = (int*)p; p += alignup((size_t)N * 4, 256);
    int* epos  = (int*)p; p += alignup((size_t)E * 4, 256);
    int* sidx  = (int*)p; p += alignup((size_t)E * 4, 256);
    bf16* Wcat = (bf16*)p; p += alignup((size_t)272 * DIN * 2, 256);
    unsigned char* yq = (unsigned char*)p; p += alignup((size_t)N * HDIM, 256);
    bf16* z    = (bf16*)p; p += alignup((size_t)N * HDIM * 2, 256);
    float* w   = (float*)p; p += alignup((size_t)N * 16 * 4, 256);

    hipMemsetAsync(cnt, 0, cntPad + 256, stream);

    int nW = 80;   // 64 wconv + 16 Wcomb
    k_histw<<<nW + (E + 255) / 256, 256, 0, stream>>>(dstv, E, cnt, epos, nW,
                                                      Wl, Wr, Wres, wscore, wcrit, Wcat);
    k_alloc<<<(N + 255) / 256, 256, 0, stream>>>(cnt, N, off, total);

    k_gemm<<<256, 512, 0, stream>>>(x, Wcat, N, yq, z, w,
                                    srcv, dstv, epos, E, off, sidx);

    float* outF = (float*)d_out;
    float* outL = outF + N;
    k_gather<<<(N + 3) / 4, 256, 0, stream>>>(yq, z, w, off, cnt, sidx, bl, bres,
                                              wscore, bscore, wcrit, bcrit,
                                              rrs, alpha, N, outF, outL);
}